// Round 16
// baseline (52.324 us; speedup 1.0000x reference)
//
#include <hip/hip_runtime.h>

// SSIM via MFMA, R16 = R15 with the cvt_pkrtz type fix (bit_cast __fp16
// vector -> _Float16 vector; same v_cvt_pkrtz_f16_f32 instruction).
// R15 theory (untested due to compile error): R8-R14 all land ~50-52us
// because waves stall ~85% of their life on serial LDS->cvt->MFMA chains
// with only 3 waves/SIMD resident (50KB LDS -> 3 blocks/CU). Halve the tile
// to 64x32 (patch 42x84 x2 = 28.2KB -> 5 blocks/CU, launch_bounds(256,5))
// for 5 waves/SIMD. Wave = (row-group rg, col-half ch); per-output work
// unchanged; H-first mfma structure + stripe-clamp (corrupts only dead
// k-slots >=26 where bbV=0) as verified in R13/R14.
// Input f32->f16 cvts: v_cvt_pkrtz (scale-consistent: products and means
// carry the same quantization scale, cancels in sigma). H->V handoff stays
// RNE scalar casts (RTZ there would re-create the R7 sigma12 bias ~1e-3).
// f16-weight-sum scale corrected by 1/t (R8).

typedef _Float16 f16;
typedef __attribute__((ext_vector_type(2))) _Float16 f16x2;
typedef __attribute__((ext_vector_type(8))) _Float16 f16x8;
typedef __attribute__((ext_vector_type(4))) float f32x4;

#define IMGW 512
#define IMGH 512
#define NPL 48           // 16*3 planes
#define NBLOCKS (NPL * 8 * 16)  // 6144: 64x32 tile per block
#define NPIX 12582912.0
#define REDT 1024

#define SRW 84                  // dword stride per patch row (21 x 16B)
#define PR 42                   // patch rows (32 outputs + 10 halo)
#define IMGOFFD (PR * SRW)      // 3528 dwords per image

// inverse of total f16-weight scale: s = sum of f16(G) = 1048748/2^20, t = s^2
#define INV_T 0.99967202f

// 11-tap gaussian, sigma=1.5, normalized (double-precision precomputed)
__device__ const float G_dev[11] = {0.00102838f, 0.00759876f, 0.03600077f,
                                    0.10936069f, 0.21300554f, 0.26601172f,
                                    0.21300554f, 0.10936069f, 0.03600077f,
                                    0.00759876f, 0.00102838f};

// pack 8 f32 -> f16x8 via v_cvt_pkrtz (inputs only; scale-consistent)
__device__ __forceinline__ f16x8 pk8(const f32x4 a, const f32x4 b) {
    const f16x2 p0 = __builtin_bit_cast(f16x2, __builtin_amdgcn_cvt_pkrtz(a[0], a[1]));
    const f16x2 p1 = __builtin_bit_cast(f16x2, __builtin_amdgcn_cvt_pkrtz(a[2], a[3]));
    const f16x2 p2 = __builtin_bit_cast(f16x2, __builtin_amdgcn_cvt_pkrtz(b[0], b[1]));
    const f16x2 p3 = __builtin_bit_cast(f16x2, __builtin_amdgcn_cvt_pkrtz(b[2], b[3]));
    return (f16x8){p0[0], p0[1], p1[0], p1[1], p2[0], p2[1], p3[0], p3[1]};
}

__global__ __launch_bounds__(256, 5) void ssim_main(const float* __restrict__ img1,
                                                    const float* __restrict__ img2,
                                                    float* __restrict__ partial) {
    __shared__ __align__(16) float sP[2 * IMGOFFD];   // 28224 B
    __shared__ float wsum[4];

    const int tid  = threadIdx.x;
    const int lane = tid & 63;
    const int wv   = tid >> 6;
    const int l15  = lane & 15;
    const int lg   = lane >> 4;        // 0..3

    const int bid   = blockIdx.x;
    const int plane = bid >> 7;        // 128 tiles per plane
    const int rem   = bid & 127;
    const int tyi   = rem >> 3;        // 0..15 (32-row bands)
    const int txi   = rem & 7;         // 0..7  (64-col tiles)
    const int R0    = tyi * 32 - 5;         // patch row 0 -> image row
    const int AC0   = txi * 64 - 8;         // patch col 0 -> image col (16B aligned)

    const float* __restrict__ p1 = img1 + (size_t)plane * (IMGH * IMGW);
    const float* __restrict__ p2 = img2 + (size_t)plane * (IMGH * IMGW);

    const bool interior = (tyi >= 1) & (tyi <= 14) & (txi >= 1) & (txi <= 6);

    // ---------- staging: async DMA ----------
    if (interior) {
        // 3 rows per issue: lanes 0..62, sub_r = lane/21, col group lane%21
        const int sub_r = lane / 21;
        const int cgl   = lane - 21 * sub_r;
        #pragma unroll
        for (int img = 0; img < 2; ++img) {
            const float* __restrict__ bp = img ? p2 : p1;
            float* lb = &sP[img * IMGOFFD];
            for (int i = wv; i < 14; i += 4) {       // rr = 0,3,...,39
                const int rr = 3 * i;
                if (lane < 63) {
                    const float* gp = bp + (size_t)(R0 + rr + sub_r) * IMGW
                                         + (AC0 + 4 * cgl);
                    __builtin_amdgcn_global_load_lds(gp, &lb[rr * SRW], 16, 0, 0);
                }
            }
        }
    } else {
        // zero whole patch, barrier, masked per-row DMA (21 lanes)
        const f32x4 zz = {0.0f, 0.0f, 0.0f, 0.0f};
        #pragma unroll
        for (int it = 0; it < 7; ++it) {
            const int i = tid + it * 256;
            if (i < 2 * IMGOFFD / 4) ((f32x4*)sP)[i] = zz;
        }
        __syncthreads();     // zeros visible before DMA writes land
        const int rlo = (R0 < 0) ? -R0 : 0;
        const int rhi = (R0 + PR > IMGH) ? (IMGH - R0) : PR;
        const bool cok = (lane < 21) &&
                         ((unsigned)(AC0 + 4 * lane) < (unsigned)IMGW);
        #pragma unroll
        for (int img = 0; img < 2; ++img) {
            const float* __restrict__ bp = img ? p2 : p1;
            float* lb = &sP[img * IMGOFFD];
            for (int r = rlo + wv; r < rhi; r += 4) {
                if (cok) {
                    const float* gp = bp + (size_t)(R0 + r) * IMGW
                                         + (AC0 + 4 * lane);
                    __builtin_amdgcn_global_load_lds(gp, &lb[r * SRW], 16, 0, 0);
                }
            }
        }
    }
    __syncthreads();   // single drain of the DMA queue

    // ---------- band fragments: B[k][n], k = kap(lg,j), n = l15 ----------
    f16x8 bbH, bbV;
    #pragma unroll
    for (int j = 0; j < 8; ++j) {
        const int kj = (j < 4) ? (4 * lg + j) : (16 + 4 * lg + (j - 4));
        const int tH = kj - l15 - 3;    // H: patch col halo offset 3
        const int tV = kj - l15;        // V: window row 0 = outrow - 5
        bbH[j] = (f16)((tH >= 0 && tH < 11) ? G_dev[tH] : 0.0f);
        bbV[j] = (f16)((tV >= 0 && tV < 11) ? G_dev[tV] : 0.0f);
    }

    const f32x4 zero4 = {0.0f, 0.0f, 0.0f, 0.0f};

    // wave roles: rg = output rows 16rg..16rg+15, ch = output cols 32ch..32ch+31
    const int rg = wv >> 1;
    const int ch = wv & 1;
    const int rowA = 16 * rg + l15;
    int rowB = rowA + 16;
    if (rowB > PR - 1) rowB = PR - 1;   // rg=1 stripe1: dead k-slots >=26, bbV=0

    float acc = 0.0f;
    const float C1 = 1.0e-4f;   // 0.01^2
    const float C2 = 9.0e-4f;   // 0.03^2

    #pragma unroll
    for (int m = 0; m < 2; ++m) {
        const int cg = 16 * (2 * ch + m) + 4 * lg;   // k-slot col group (16B aligned)
        f32x4 D0[5], D1[5];
        #pragma unroll
        for (int s = 0; s < 2; ++s) {
            const int row = s ? rowB : rowA;
            const float* __restrict__ r1 = &sP[row * SRW];
            const float* __restrict__ r2 = &sP[IMGOFFD + row * SRW];
            const f32x4 xa = *(const f32x4*)&r1[cg];
            const f32x4 xb = *(const f32x4*)&r1[cg + 16];
            const f32x4 ya = *(const f32x4*)&r2[cg];
            const f32x4 yb = *(const f32x4*)&r2[cg + 16];
            const f16x8 fx = pk8(xa, xb);
            const f16x8 fy = pk8(ya, yb);
            const f16x8 fxx = fx * fx;   // v_pk_mul_f16
            const f16x8 fyy = fy * fy;
            const f16x8 fxy = fx * fy;
            f32x4* D = s ? D1 : D0;
            D[0] = __builtin_amdgcn_mfma_f32_16x16x32_f16(fx,  bbH, zero4, 0, 0, 0);
            D[1] = __builtin_amdgcn_mfma_f32_16x16x32_f16(fy,  bbH, zero4, 0, 0, 0);
            D[2] = __builtin_amdgcn_mfma_f32_16x16x32_f16(fxx, bbH, zero4, 0, 0, 0);
            D[3] = __builtin_amdgcn_mfma_f32_16x16x32_f16(fyy, bbH, zero4, 0, 0, 0);
            D[4] = __builtin_amdgcn_mfma_f32_16x16x32_f16(fxy, bbH, zero4, 0, 0, 0);
        }
        // V-pass: lane's H outputs (rows 4lg+reg per stripe, col l15) ARE its
        // A-fragment. RNE scalar casts here (RTZ would bias sigma12, see R7).
        f32x4 h[5];
        #pragma unroll
        for (int q = 0; q < 5; ++q) {
            f16x8 av;
            #pragma unroll
            for (int j = 0; j < 4; ++j) {
                av[j]     = (f16)D0[q][j];
                av[j + 4] = (f16)D1[q][j];
            }
            h[q] = __builtin_amdgcn_mfma_f32_16x16x32_f16(av, bbV, zero4, 0, 0, 0);
            h[q] *= INV_T;   // remove f16-weight-sum scale (s^2 per quantity)
        }
        #pragma unroll
        for (int r = 0; r < 4; ++r) {
            const float mu1 = h[0][r], mu2 = h[1][r];
            const float exx = h[2][r], eyy = h[3][r], exy = h[4][r];
            const float mu1s = mu1 * mu1;
            const float mu2s = mu2 * mu2;
            const float mu12 = mu1 * mu2;
            const float s1  = exx - mu1s;
            const float s2  = eyy - mu2s;
            const float s12 = exy - mu12;
            const float num = fmaf(2.0f, mu12, C1) * fmaf(2.0f, s12, C2);
            const float den = (mu1s + mu2s + C1) * (s1 + s2 + C2);
            float rd = __builtin_amdgcn_rcpf(den);   // den > 0 always
            rd = rd * fmaf(-den, rd, 2.0f);          // Newton step
            acc = fmaf(num, rd, acc);
        }
    }

    // ---------- block reduction ----------
    #pragma unroll
    for (int off = 32; off > 0; off >>= 1)
        acc += __shfl_down(acc, off, 64);
    if (lane == 0) wsum[wv] = acc;
    __syncthreads();
    if (tid == 0)
        partial[bid] = (wsum[0] + wsum[1]) + (wsum[2] + wsum[3]);
}

__global__ __launch_bounds__(REDT) void ssim_reduce(const float* __restrict__ partial,
                                                    float* __restrict__ out) {
    const int tid = threadIdx.x;
    double s = 0.0;
    for (int i = tid; i < NBLOCKS; i += REDT)
        s += (double)partial[i];
    #pragma unroll
    for (int off = 32; off > 0; off >>= 1)
        s += __shfl_down(s, off, 64);
    __shared__ double wsd[REDT / 64];
    if ((tid & 63) == 0) wsd[tid >> 6] = s;
    __syncthreads();
    if (tid == 0) {
        double t = 0.0;
        #pragma unroll
        for (int i = 0; i < REDT / 64; ++i) t += wsd[i];
        out[0] = (float)(t / NPIX);
    }
}

extern "C" void kernel_launch(void* const* d_in, const int* in_sizes, int n_in,
                              void* d_out, int out_size, void* d_ws, size_t ws_size,
                              hipStream_t stream) {
    const float* img1 = (const float*)d_in[0];
    const float* img2 = (const float*)d_in[1];
    float* partial = (float*)d_ws;      // 6144 floats = 24.6 KB
    float* out = (float*)d_out;
    ssim_main<<<NBLOCKS, 256, 0, stream>>>(img1, img2, partial);
    ssim_reduce<<<1, REDT, 0, stream>>>(partial, out);
}